// Round 9
// baseline (323.836 us; speedup 1.0000x reference)
//
#include <hip/hip_runtime.h>
#include <hip/hip_cooperative_groups.h>

namespace cg = cooperative_groups;

// Problem constants (match reference)
#define NX_ 64
#define NY_ 64
#define NBINS 128
#define NSUB 10
#define NV (NSUB * NBINS)      // 1280
#define PADL NV                // 1280
#define ROWLEN (NV + 2 * PADL) // 3840
#define BATCH 32
#define NROWS (NY_ * NX_)          // 4096
#define CELLS (BATCH * NY_ * NX_)  // 131072
#define CAP 128                    // bucket capacity per row (avg 32, max ~77 expected)
#define TABN (BATCH * NBINS)       // 4096
#define GRID_ 1024                 // 4 blocks/CU * 256 CU -> fully co-resident
#define TPB 512

// One cooperative kernel, three phases separated by grid syncs:
//   0: zero cnt (8 blocks' worth of threads) + per-block LDS v-idx table +
//      row-independent span bounds         [tabl: bit-parity f32 linspace]
//   1: bin each cell by its (yi,xi) row    [atomicAdd bucket; CAP overflow
//      serves the cell directly — statistically never taken]
//   2: each block serves NROWS/GRID_ = 4 rows: stage union span into LDS
//      (float4), serve cells from LDS. Lane k-map = lane + 32j -> span
//      stride ~10 floats across lanes (~4-way bank alias, near-free);
//      tabl reads consecutive (conflict-free); stores stride-1 coalesced.
__global__ __launch_bounds__(TPB, 8) void fused_kernel(
    const float* __restrict__ cur_pos,   // (B,64,64,2)
    const float* __restrict__ deltas,    // (B,3)
    const int* __restrict__ is_cam,
    const float* __restrict__ voxel,     // (64,64,3840)
    int* __restrict__ cnt,               // (4096) ws
    unsigned* __restrict__ bucket,       // (4096, CAP) ws
    float* __restrict__ out,             // (B,64,64,128)
    float vr_f, float vbase_f)
{
    __shared__ __align__(16) float span[ROWLEN];  // 15 KB
    __shared__ int tabl[TABN];                    // 16 KB
    __shared__ unsigned s_cells[CAP];
    __shared__ int s_lo, s_hi;

    cg::grid_group gg = cg::this_grid();
    int tid = threadIdx.x;
    int gtid = blockIdx.x * TPB + tid;

    // ---- phase 0 ----
    if (gtid < NROWS) cnt[gtid] = 0;
    float step = vr_f / 127.0f;
    #pragma unroll
    for (int i = tid; i < TABN; i += TPB) {
        int b = i >> 7;
        int k = i & (NBINS - 1);
        float dv = deltas[b * 3 + 2];
        float xl = (k == NBINS - 1) ? vr_f : (float)k * step;
        tabl[i] = PADL + (int)((-dv + xl) / vbase_f);
    }
    __syncthreads();
    if (tid < 64) {
        int bb = tid & 31;
        int lo = tabl[bb * 128];
        int hi = tabl[bb * 128 + 127];
        #pragma unroll
        for (int m = 16; m >= 1; m >>= 1) {
            lo = min(lo, __shfl_xor(lo, m));
            hi = max(hi, __shfl_xor(hi, m));
        }
        if (tid == 0) {
            s_lo = max(lo, 0);
            s_hi = min(hi, ROWLEN - 1);
        }
    }
    gg.sync();

    // ---- phase 1: bin ----
    if (gtid < CELLS) {
        int cell = gtid;
        int b = cell >> 12;  // 4096 cells per batch
        float sign = (is_cam[0] != 0) ? 1.0f : -1.0f;
        float2 p = ((const float2*)cur_pos)[cell];
        float dx = deltas[b * 3 + 0];
        float dy = deltas[b * 3 + 1];
        float xs = fminf(fmaxf(p.x + sign * dx, -1.0f), 1.0f);
        float ys = fminf(fmaxf(p.y + sign * dy, -1.0f), 1.0f);
        int xi = (int)(32.0f * (xs + 1.0f));
        int yi = (int)(32.0f * (ys + 1.0f));
        xi = min(max(xi, 0), NX_ - 1);
        yi = min(max(yi, 0), NY_ - 1);
        int r = yi * NX_ + xi;
        int pos = atomicAdd(&cnt[r], 1);
        if (pos < CAP) {
            bucket[r * CAP + pos] = (unsigned)cell;
        } else {
            // slow path: serve directly from global (correctness net)
            const float* __restrict__ row = voxel + (size_t)r * ROWLEN;
            float* __restrict__ o = out + (size_t)cell * NBINS;
            for (int k = 0; k < NBINS; ++k) o[k] = row[tabl[(b << 7) + k]];
        }
    }
    gg.sync();

    // ---- phase 2: serve 4 rows per block ----
    int lo4 = s_lo & ~3;
    int end4 = (s_hi + 4) & ~3;   // (hi inclusive +1, round up to x4)
    if (end4 > ROWLEN) end4 = ROWLEN;
    int nvec = (end4 - lo4) >> 2;
    int g = tid >> 5, lane = tid & 31;

    for (int r = blockIdx.x; r < NROWS; r += GRID_) {
        int n = cnt[r];          // block-uniform
        if (n > CAP) n = CAP;
        __syncthreads();         // WAR on span/s_cells vs previous row's serve
        if (n > 0) {
            if (tid < n) s_cells[tid] = bucket[r * CAP + tid];
            const float4* __restrict__ row4 =
                (const float4*)(voxel + (size_t)r * ROWLEN) + (lo4 >> 2);
            float4* span4 = (float4*)span;
            for (int i = tid; i < nvec; i += TPB) span4[i] = row4[i];
        }
        __syncthreads();
        if (n > 0) {
            for (int ci = g; ci < n; ci += TPB / 32) {
                unsigned cell = s_cells[ci];
                int b = (int)(cell >> 12);
                const int* t = tabl + b * NBINS;
                int i0 = t[lane]      - lo4;
                int i1 = t[lane + 32] - lo4;
                int i2 = t[lane + 64] - lo4;
                int i3 = t[lane + 96] - lo4;
                float v0 = span[i0], v1 = span[i1], v2 = span[i2], v3 = span[i3];
                float* __restrict__ o = out + (size_t)cell * NBINS;
                o[lane]      = v0;
                o[lane + 32] = v1;
                o[lane + 64] = v2;
                o[lane + 96] = v3;
            }
        }
    }
}

extern "C" void kernel_launch(void* const* d_in, const int* in_sizes, int n_in,
                              void* d_out, int out_size, void* d_ws, size_t ws_size,
                              hipStream_t stream) {
    const float* cur_pos = (const float*)d_in[0];
    const float* deltas  = (const float*)d_in[1];
    const float* voxel   = (const float*)d_in[2];
    const int*   is_cam  = (const int*)d_in[3];
    float* out = (float*)d_out;

    // d_ws layout: cnt (16 KB) | bucket (2 MB)
    int* cnt = (int*)d_ws;
    unsigned* bucket = (unsigned*)(cnt + NROWS);

    const double vr_d = ((3.0e8 * 128.0) * 32e-12 / 2.0) * ((3.0e8 * 128.0) * 32e-12 / 2.0);
    float vr_f = (float)vr_d;
    float vbase_f = (float)(vr_d / (double)NV);

    void* args[] = { (void*)&cur_pos, (void*)&deltas, (void*)&is_cam,
                     (void*)&voxel, (void*)&cnt, (void*)&bucket, (void*)&out,
                     (void*)&vr_f, (void*)&vbase_f };

    hipLaunchCooperativeKernel((const void*)fused_kernel, dim3(GRID_), dim3(TPB),
                               args, 0, stream);
}